// Round 1
// baseline (409.761 us; speedup 1.0000x reference)
//
#include <hip/hip_runtime.h>

// Problem:
//   fc_out[b,o] = sum_k concat_gap[b,k] * weight[o,k] + bias[o]      (16x3)
//   vis_i[b,0,d,h,w] = sum_c out_i[b,c,d,h,w] * 0.5*(weight[0,c+off]+weight[1,c+off])
// Output layout (flat f32): fc_out(48) | vis1(983040) | vis2(131072) | vis3(16384)
//
// Memory-bound: ~335 MB read, ~4.5 MB write -> roofline ~54 us @ 6.3 TB/s.
//
// Block partition (heavy-first to avoid straggler tail):
//   [0,16)      vis3: C=256, S4/batch=256,   1 block/batch   (1 MB read/block)
//   [16,144)    vis2: C=128, S4/batch=2048,  8 blocks/batch  (512 KB/block)
//   [144,1104)  vis1: C=64,  S4/batch=15360, 60 blocks/batch (256 KB/block)
//   1104        fc (tiny)

#define VIS3_BLOCKS 16
#define VIS2_BLOCKS 128
#define VIS1_BLOCKS 960
#define TOTAL_BLOCKS (VIS3_BLOCKS + VIS2_BLOCKS + VIS1_BLOCKS + 1)

__global__ __launch_bounds__(256) void fused_vis_fc_kernel(
    const float* __restrict__ concat_gap,   // [16,448]
    const float* __restrict__ out1,         // [16,64,61440]
    const float* __restrict__ out2,         // [16,128,8192]
    const float* __restrict__ out3,         // [16,256,1024]
    const float* __restrict__ weight,       // [3,448]
    const float* __restrict__ bias,         // [3]
    float* __restrict__ d_out)
{
    const int t = threadIdx.x;
    int blk = blockIdx.x;

    const float* in;
    float* out;
    int C, bpb, woff;

    if (blk < VIS3_BLOCKS) {
        in = out3; out = d_out + 48 + 983040 + 131072;
        C = 256; bpb = 1; woff = 192;
    } else if (blk < VIS3_BLOCKS + VIS2_BLOCKS) {
        blk -= VIS3_BLOCKS;
        in = out2; out = d_out + 48 + 983040;
        C = 128; bpb = 8; woff = 64;
    } else if (blk < VIS3_BLOCKS + VIS2_BLOCKS + VIS1_BLOCKS) {
        blk -= VIS3_BLOCKS + VIS2_BLOCKS;
        in = out1; out = d_out + 48;
        C = 64; bpb = 60; woff = 0;
    } else {
        // fc block: 48 outputs, each thread does one 448-length dot product.
        // Tiny (28 KB of input, L2-resident); runs concurrently with vis blocks.
        if (t < 48) {
            const int b = t / 3, o = t % 3;
            const float* g = concat_gap + b * 448;
            const float* w = weight + o * 448;
            float s = 0.f;
            #pragma unroll 8
            for (int k = 0; k < 448; ++k) s += g[k] * w[k];
            d_out[t] = s + bias[o];
        }
        return;
    }

    // Stage effective weights: w_eff[c] = 0.5*(weight[0][woff+c] + weight[1][woff+c])
    __shared__ float s_w[256];
    for (int c = t; c < C; c += 256)
        s_w[c] = 0.5f * (weight[woff + c] + weight[448 + woff + c]);
    __syncthreads();

    const int b  = blk / bpb;             // batch index
    const int s4 = (blk % bpb) * 256 + t; // float4 index within batch spatial
    const int S4 = bpb * 256;             // float4s per (batch, channel) plane

    const float4* in4 = (const float4*)in + (size_t)b * C * S4 + s4;

    float4 acc = make_float4(0.f, 0.f, 0.f, 0.f);
    #pragma unroll 8
    for (int c = 0; c < C; ++c) {
        float4 v = in4[(size_t)c * S4];   // wave reads 1 KiB contiguous per iter
        const float w = s_w[c];
        acc.x += v.x * w;
        acc.y += v.y * w;
        acc.z += v.z * w;
        acc.w += v.w * w;
    }
    ((float4*)out)[(size_t)b * S4 + s4] = acc;
}

extern "C" void kernel_launch(void* const* d_in, const int* in_sizes, int n_in,
                              void* d_out, int out_size, void* d_ws, size_t ws_size,
                              hipStream_t stream) {
    const float* concat_gap = (const float*)d_in[0];
    const float* out1       = (const float*)d_in[1];
    const float* out2       = (const float*)d_in[2];
    const float* out3       = (const float*)d_in[3];
    const float* weight     = (const float*)d_in[4];
    const float* bias       = (const float*)d_in[5];
    float* out              = (float*)d_out;

    fused_vis_fc_kernel<<<TOTAL_BLOCKS, 256, 0, stream>>>(
        concat_gap, out1, out2, out3, weight, bias, out);
}

// Round 2
// 370.396 us; speedup vs baseline: 1.1063x; 1.1063x over previous
//
#include <hip/hip_runtime.h>

// fc_out[b,o] = concat_gap[b,:]·weight[o,:] + bias[o]           (16x3)
// vis_i[b,0,s] = sum_c out_i[b,c,s] * 0.5*(weight[0,c+off]+weight[1,c+off])
// Output flat f32: fc(48) | vis1(983040) | vis2(131072) | vis3(16384)
//
// All sizes in float4 units:
//   out1: [16][64][15360]   out2: [16][128][2048]   out3: [16][256][256]
// Traffic: 335 MB read + 4.5 MB write -> ~54 us floor @ 6.3 TB/s.
//
// Grid: 641 equal-cost (512 KB read) blocks, compile-time-specialized paths:
//   [0,32)    vis3: 2 blocks/batch, channel-split 2x128 + LDS combine
//   [32,160)  vis2: 8 blocks/batch, 256-f4 chunk, C=128
//   [160,640) vis1: 30 blocks/batch, 512-f4 chunk (2 f4/thread), C=64
//   640       fc

typedef float fvec4 __attribute__((ext_vector_type(4)));

__device__ __forceinline__ fvec4 ntload(const fvec4* p) {
    return __builtin_nontemporal_load(p);
}
__device__ __forceinline__ void ntstore(fvec4* p, fvec4 v) {
    __builtin_nontemporal_store(v, p);
}

__global__ __launch_bounds__(256) void fused_vis_fc_v2(
    const float* __restrict__ concat_gap,
    const float* __restrict__ out1,
    const float* __restrict__ out2,
    const float* __restrict__ out3,
    const float* __restrict__ weight,
    const float* __restrict__ bias,
    float* __restrict__ d_out)
{
    const int t = threadIdx.x;
    int blk = blockIdx.x;

    __shared__ float s_w[256];
    __shared__ fvec4 s_red[128];

    if (blk < 32) {
        // ---- vis3: C=256 split across thread halves, S4=256 ----
        const int b    = blk >> 1;
        const int s4   = ((blk & 1) << 7) + (t & 127);   // [0,256)
        const int half = t >> 7;                          // 0 or 1
        for (int c = t; c < 256; c += 256)
            s_w[c] = 0.5f * (weight[192 + c] + weight[640 + c]);
        __syncthreads();

        const fvec4* in4 = (const fvec4*)out3
            + (size_t)b * 256 * 256 + (size_t)(half * 128) * 256 + s4;
        fvec4 acc = {0.f, 0.f, 0.f, 0.f};
        #pragma unroll 8
        for (int c = 0; c < 128; ++c)
            acc += ntload(in4 + (size_t)c * 256) * s_w[half * 128 + c];

        if (half) s_red[t & 127] = acc;
        __syncthreads();
        if (!half) {
            acc += s_red[t];
            ntstore((fvec4*)(d_out + 48 + 983040 + 131072) + b * 256 + s4, acc);
        }
    } else if (blk < 160) {
        // ---- vis2: C=128, S4=2048, 256-f4 chunk ----
        blk -= 32;
        const int b  = blk >> 3;
        const int s4 = ((blk & 7) << 8) + t;              // [0,2048)
        for (int c = t; c < 128; c += 256)
            s_w[c] = 0.5f * (weight[64 + c] + weight[512 + c]);
        __syncthreads();

        const fvec4* in4 = (const fvec4*)out2 + (size_t)b * 128 * 2048 + s4;
        fvec4 acc = {0.f, 0.f, 0.f, 0.f};
        #pragma unroll 8
        for (int c = 0; c < 128; ++c)
            acc += ntload(in4 + (size_t)c * 2048) * s_w[c];
        ntstore((fvec4*)(d_out + 48 + 983040) + b * 2048 + s4, acc);
    } else if (blk < 640) {
        // ---- vis1: C=64, S4=15360, 512-f4 chunk, 2 f4/thread ----
        blk -= 160;
        const int b     = blk / 30;
        const int chunk = (blk % 30) * 512;
        for (int c = t; c < 64; c += 256)
            s_w[c] = 0.5f * (weight[c] + weight[448 + c]);
        __syncthreads();

        const fvec4* in4 = (const fvec4*)out1
            + (size_t)b * 64 * 15360 + chunk + t;
        fvec4 a0 = {0.f, 0.f, 0.f, 0.f};
        fvec4 a1 = {0.f, 0.f, 0.f, 0.f};
        #pragma unroll 8
        for (int c = 0; c < 64; ++c) {
            const float w = s_w[c];
            a0 += ntload(in4 + (size_t)c * 15360) * w;
            a1 += ntload(in4 + (size_t)c * 15360 + 256) * w;
        }
        fvec4* o = (fvec4*)(d_out + 48) + (size_t)b * 15360 + chunk + t;
        ntstore(o, a0);
        ntstore(o + 256, a1);
    } else {
        // ---- fc: 16x3 addmm, L2-resident, overlaps with vis blocks ----
        if (t < 48) {
            const int b = t / 3, o = t % 3;
            const float* g = concat_gap + b * 448;
            const float* w = weight + o * 448;
            float s = 0.f;
            #pragma unroll 8
            for (int k = 0; k < 448; ++k) s += g[k] * w[k];
            d_out[t] = s + bias[o];
        }
    }
}

extern "C" void kernel_launch(void* const* d_in, const int* in_sizes, int n_in,
                              void* d_out, int out_size, void* d_ws, size_t ws_size,
                              hipStream_t stream) {
    fused_vis_fc_v2<<<641, 256, 0, stream>>>(
        (const float*)d_in[0], (const float*)d_in[1], (const float*)d_in[2],
        (const float*)d_in[3], (const float*)d_in[4], (const float*)d_in[5],
        (float*)d_out);
}